// Round 11
// baseline (1780.788 us; speedup 1.0000x reference)
//
#include <hip/hip_runtime.h>
#include <stdint.h>

#pragma clang fp contract(off)

typedef unsigned long long u64;
typedef float __attribute__((ext_vector_type(2))) f32x2;

#define NBATCH 16
#define NPTS   4096
#define NCH    64
#define NPOINT 1024
#define NSAMP  32

// ---- workspace byte offsets ----
#define OFF_FEATT   0u          // 16*4096*64*4 = 16777216
#define OFF_NEWXYZ  16777216u   // 16*1024*3*4 = 196608
#define OFF_GIDX    16973824u   // 16*1024*32*4 = 2097152
#define OFF_WT0     19070976u   // 67*64*4 = 17152
#define OFF_BP0     19088128u   // 64*4 (pad 256)
#define OFF_WT1     19088384u   // 64*64*4 = 16384
#define OFF_BP1     19104768u   // pad 256
#define OFF_WT2     19105024u   // 64*128*4 = 32768
#define OFF_BP2     19137792u   // pad 512
#define WS_NEED     19138304u

// Monotone map: float bits -> unsigned preserving total order (neg < pos).
__device__ __forceinline__ unsigned fkey(float f) {
  unsigned b = __float_as_uint(f);
  unsigned mask = ((unsigned)((int)b >> 31)) | 0x80000000u;
  return b ^ mask;
}

__device__ __forceinline__ double mkkey(float v, unsigned lo) {
  // key = (bits(v) << 32) | lo, viewed as double. v in [0, 1e10] -> positive
  // double, never NaN/Inf -> u64 order == f64 order -> fmax == u64 max.
  return __longlong_as_double((long long)(((u64)__float_as_uint(v) << 32) | lo));
}

__device__ __forceinline__ int mbcnt64(u64 m) {
  int c = __builtin_amdgcn_mbcnt_lo((unsigned)m, 0);
  return __builtin_amdgcn_mbcnt_hi((unsigned)(m >> 32), c);
}

// max over the 32-lane half this lane sits in; valid in lanes 16-31 / 48-63.
// Inputs are post-ReLU (>=0, no NaN) so fmaxf order-exact.
__device__ __forceinline__ float dppmax32(float v) {
  int x = __float_as_int(v);
#define DSTEP(CTRL)                                                        \
  {                                                                        \
    int y = __builtin_amdgcn_update_dpp(x, x, CTRL, 0xF, 0xF, false);      \
    v = fmaxf(v, __int_as_float(y));                                       \
    x = __float_as_int(v);                                                 \
  }
  DSTEP(0xB1)   // quad_perm xor1
  DSTEP(0x4E)   // quad_perm xor2
  DSTEP(0x124)  // row_ror:4
  DSTEP(0x128)  // row_ror:8   -> 16-rows uniform
  DSTEP(0x142)  // row_bcast15 -> lanes 16-31 / 48-63 hold the 32-half max
#undef DSTEP
  return v;
}

// ---------------------------------------------------------------------------
// Fold BN (eval) into conv weights/bias; transpose W to [c][o].
// ---------------------------------------------------------------------------
__global__ __launch_bounds__(256) void prep_kernel(
    const float* __restrict__ W0, const float* __restrict__ b0, const float* __restrict__ g0,
    const float* __restrict__ be0, const float* __restrict__ m0, const float* __restrict__ v0,
    const float* __restrict__ W1, const float* __restrict__ b1, const float* __restrict__ g1,
    const float* __restrict__ be1, const float* __restrict__ m1, const float* __restrict__ v1,
    const float* __restrict__ W2, const float* __restrict__ b2, const float* __restrict__ g2,
    const float* __restrict__ be2, const float* __restrict__ m2, const float* __restrict__ v2,
    float* __restrict__ wt0, float* __restrict__ bp0,
    float* __restrict__ wt1, float* __restrict__ bp1,
    float* __restrict__ wt2, float* __restrict__ bp2) {
  int t = threadIdx.x;
  for (int i = t; i < 64 * 67; i += 256) {
    int o = i / 67, c = i % 67;
    float s = g0[o] / sqrtf(v0[o] + 1e-5f);
    wt0[c * 64 + o] = W0[o * 67 + c] * s;
  }
  for (int o = t; o < 64; o += 256) {
    float s = g0[o] / sqrtf(v0[o] + 1e-5f);
    bp0[o] = (b0[o] - m0[o]) * s + be0[o];
  }
  for (int i = t; i < 64 * 64; i += 256) {
    int o = i / 64, c = i % 64;
    float s = g1[o] / sqrtf(v1[o] + 1e-5f);
    wt1[c * 64 + o] = W1[o * 64 + c] * s;
  }
  for (int o = t; o < 64; o += 256) {
    float s = g1[o] / sqrtf(v1[o] + 1e-5f);
    bp1[o] = (b1[o] - m1[o]) * s + be1[o];
  }
  for (int i = t; i < 128 * 64; i += 256) {
    int o = i / 64, c = i % 64;
    float s = g2[o] / sqrtf(v2[o] + 1e-5f);
    wt2[c * 128 + o] = W2[o * 64 + c] * s;
  }
  for (int o = t; o < 128; o += 256) {
    float s = g2[o] / sqrtf(v2[o] + 1e-5f);
    bp2[o] = (b2[o] - m2[o]) * s + be2[o];
  }
}

// ---------------------------------------------------------------------------
// features [B,C,N] -> featT [B,N,C]  (tiled 32x32 transpose)
// ---------------------------------------------------------------------------
__global__ __launch_bounds__(256) void transpose_kernel(const float* __restrict__ feat,
                                                        float* __restrict__ featT) {
  __shared__ float tile[32][33];
  int b = blockIdx.z;
  int n0 = blockIdx.x * 32;
  int c0 = blockIdx.y * 32;
  int tx = threadIdx.x, ty = threadIdx.y;  // 32 x 8
#pragma unroll
  for (int j = 0; j < 4; ++j)
    tile[ty + 8 * j][tx] = feat[b * (NCH * NPTS) + (c0 + ty + 8 * j) * NPTS + n0 + tx];
  __syncthreads();
#pragma unroll
  for (int j = 0; j < 4; ++j)
    featT[b * (NPTS * NCH) + (size_t)(n0 + ty + 8 * j) * NCH + c0 + tx] = tile[tx][ty + 8 * j];
}

// ---------------------------------------------------------------------------
// Exact farthest-point sampling. One block per batch, 256 threads x 16 pts
// (8x f32x2 packed). f64-key argmax (R4/R6 scheme). Measured 507 us (R9).
// ---------------------------------------------------------------------------
#define DPP_MAXSTEP(CTRL)                                                                          \
  do {                                                                                             \
    u64 kb_ = (u64)__double_as_longlong(key);                                                      \
    unsigned lo_ = (unsigned)kb_, hi_ = (unsigned)(kb_ >> 32);                                     \
    unsigned slo = (unsigned)__builtin_amdgcn_update_dpp((int)lo_, (int)lo_, CTRL, 0xF, 0xF, false); \
    unsigned shi = (unsigned)__builtin_amdgcn_update_dpp((int)hi_, (int)hi_, CTRL, 0xF, 0xF, false); \
    key = fmax(key, __longlong_as_double((long long)(((u64)shi << 32) | slo)));                    \
  } while (0)

__global__ __launch_bounds__(256) void fps_kernel(const float* __restrict__ xyz,
                                                  float* __restrict__ nxyz,
                                                  float* __restrict__ out_xyz) {
  __shared__ float sx[NPTS], sy[NPTS], sz[NPTS];
  __shared__ float outc[NPOINT][3];
  __shared__ double wkd[2][4];
  int b = blockIdx.x;
  int t = threadIdx.x;
  const float* X = xyz + (size_t)b * NPTS * 3;

  f32x2 qx[8], qy[8], qz[8], d2[8];
  unsigned nio[16];  // ~global_idx, loop-invariant key low words
#pragma unroll
  for (int i = 0; i < 8; ++i) {
    int p0 = t + 256 * (2 * i);
    int p1 = t + 256 * (2 * i + 1);
    float x0 = X[p0 * 3 + 0], y0 = X[p0 * 3 + 1], z0 = X[p0 * 3 + 2];
    float x1 = X[p1 * 3 + 0], y1 = X[p1 * 3 + 1], z1 = X[p1 * 3 + 2];
    qx[i].x = x0; qx[i].y = x1;
    qy[i].x = y0; qy[i].y = y1;
    qz[i].x = z0; qz[i].y = z1;
    sx[p0] = x0; sy[p0] = y0; sz[p0] = z0;
    sx[p1] = x1; sy[p1] = y1; sz[p1] = z1;
    d2[i].x = 1e10f; d2[i].y = 1e10f;
    nio[2 * i] = ~(unsigned)p0;
    nio[2 * i + 1] = ~(unsigned)p1;
  }
  __syncthreads();

  float lx = sx[0], ly = sy[0], lz = sz[0];
  if (t == 0) { outc[0][0] = lx; outc[0][1] = ly; outc[0][2] = lz; }

  for (int k = 1; k < NPOINT; ++k) {
    f32x2 vlx; vlx.x = lx; vlx.y = lx;
    f32x2 vly; vly.x = ly; vly.y = ly;
    f32x2 vlz; vlz.x = lz; vlz.y = lz;
    // distance update: contract(off), exact per-component order (dx^2+dy^2)+dz^2
#pragma unroll
    for (int i = 0; i < 8; ++i) {
      f32x2 dx = qx[i] - vlx, dy = qy[i] - vly, dz = qz[i] - vlz;
      f32x2 dist = (dx * dx + dy * dy) + dz * dz;
      d2[i] = __builtin_elementwise_min(d2[i], dist);
    }
    // 16 keys -> 15 v_max_f64 tree
    double k0 = fmax(mkkey(d2[0].x, nio[0]), mkkey(d2[0].y, nio[1]));
    double k1 = fmax(mkkey(d2[1].x, nio[2]), mkkey(d2[1].y, nio[3]));
    double k2 = fmax(mkkey(d2[2].x, nio[4]), mkkey(d2[2].y, nio[5]));
    double k3 = fmax(mkkey(d2[3].x, nio[6]), mkkey(d2[3].y, nio[7]));
    double k4 = fmax(mkkey(d2[4].x, nio[8]), mkkey(d2[4].y, nio[9]));
    double k5 = fmax(mkkey(d2[5].x, nio[10]), mkkey(d2[5].y, nio[11]));
    double k6 = fmax(mkkey(d2[6].x, nio[12]), mkkey(d2[6].y, nio[13]));
    double k7 = fmax(mkkey(d2[7].x, nio[14]), mkkey(d2[7].y, nio[15]));
    k0 = fmax(k0, k1); k2 = fmax(k2, k3); k4 = fmax(k4, k5); k6 = fmax(k6, k7);
    k0 = fmax(k0, k2); k4 = fmax(k4, k6);
    double key = fmax(k0, k4);

    // wave64 max-reduce; lane 63 ends with the wave max
    DPP_MAXSTEP(0xB1);   // quad_perm xor1
    DPP_MAXSTEP(0x4E);   // quad_perm xor2
    DPP_MAXSTEP(0x124);  // row_ror:4
    DPP_MAXSTEP(0x128);  // row_ror:8
    DPP_MAXSTEP(0x142);  // row_bcast15
    DPP_MAXSTEP(0x143);  // row_bcast31

    int kb = k & 1;
    if ((t & 63) == 63) wkd[kb][t >> 6] = key;
    __syncthreads();
    double w0 = wkd[kb][0], w1 = wkd[kb][1], w2 = wkd[kb][2], w3 = wkd[kb][3];
    w0 = fmax(w0, w1); w2 = fmax(w2, w3);
    w0 = fmax(w0, w2);
    int last = (int)(~(unsigned)(u64)__double_as_longlong(w0));
    lx = sx[last]; ly = sy[last]; lz = sz[last];  // broadcast LDS reads
    if (t == 0) { outc[k][0] = lx; outc[k][1] = ly; outc[k][2] = lz; }
    // no second barrier: wkd double-buffered on k&1
  }
  __syncthreads();
  for (int p = t; p < NPOINT; p += 256) {
    float x = outc[p][0], y = outc[p][1], z = outc[p][2];
    int o = (b * NPOINT + p) * 3;
    nxyz[o] = x; nxyz[o + 1] = y; nxyz[o + 2] = z;
    out_xyz[o] = x; out_xyz[o + 1] = y; out_xyz[o + 2] = z;
  }
}

// ---------------------------------------------------------------------------
// 32 nearest neighbors per sampled point — wave-per-query radix-rank select.
// Registers-only, no LDS, no barriers (R8: part of the -210us gain).
// ---------------------------------------------------------------------------
__global__ __launch_bounds__(256) void topk_kernel(const float* __restrict__ xyz,
                                                   const float* __restrict__ nxyz,
                                                   int* __restrict__ gidx) {
  int wq = (blockIdx.x << 2) + (threadIdx.x >> 6);  // query id: b*1024 + p
  int lane = threadIdx.x & 63;
  int b = wq >> 10;
  const float* X = xyz + (size_t)b * NPTS * 3;
  float px = nxyz[wq * 3 + 0], py = nxyz[wq * 3 + 1], pz = nxyz[wq * 3 + 2];
  float n2p = (px * px + py * py) + pz * pz;

  unsigned ukey[64];
#pragma unroll
  for (int i = 0; i < 64; ++i) {
    int n = i * 64 + lane;
    float x = X[n * 3 + 0], y = X[n * 3 + 1], z = X[n * 3 + 2];
    float n2x = (x * x + y * y) + z * z;
    float dot = fmaf(pz, z, fmaf(py, y, px * x));
    float sq = (n2p + n2x) - 2.0f * dot;
    ukey[i] = fkey(sq);
  }

  // V* = max V with count(ukey < V) <= 31  == 32nd-smallest ukey value
  unsigned V = 0u;
  for (int bit = 31; bit >= 0; --bit) {
    unsigned cand = V | (1u << bit);
    int cnt = 0;
#pragma unroll
    for (int i = 0; i < 64; ++i)
      cnt += __popcll(__ballot(ukey[i] < cand));
    if (cnt <= 31) V = cand;
  }

  int* go = gidx + (size_t)wq * NSAMP;
  int base = 0;
#pragma unroll
  for (int i = 0; i < 64; ++i) {  // all strictly-below-threshold keys
    bool lt = ukey[i] < V;
    u64 m = __ballot(lt);
    if (lt) go[base + mbcnt64(m)] = i * 64 + lane;
    base += __popcll(m);
  }
#pragma unroll
  for (int i = 0; i < 64; ++i) {  // fill from ==V* by ascending idx
    bool eq = (ukey[i] == V);
    u64 m = __ballot(eq);
    if (eq) {
      int pos = base + mbcnt64(m);
      if (pos < NSAMP) go[pos] = i * 64 + lane;
    }
    base += __popcll(m);
  }
}

// ---------------------------------------------------------------------------
// Gather + 3-layer pointwise MLP (BN folded) + max over 32 samples.
// RESTRUCTURED: one lane = one sample end-to-end. Block = 8 points (256
// threads = 256 samples). Only the gathered input lives in LDS (1 barrier);
// L0 output (64ch) stays in REGISTERS; L1/L2 fully unrolled (static register
// indexing) consume registers directly — no inter-layer LDS, no barriers,
// 67 ds_reads/lane (was 195). Weight rows now wave-uniform over all channels
// -> scalar-load stream hoisted across the unrolled body. Maxpool over the
// 32 s-lanes via 5-step DPP chain (VALU) instead of 160 ds_bpermute.
// ---------------------------------------------------------------------------
__global__ __launch_bounds__(256) void mlp_kernel(
    const float* __restrict__ xyz, const float* __restrict__ featT,
    const float* __restrict__ nxyz, const int* __restrict__ gidx,
    const float* __restrict__ wt0, const float* __restrict__ bp0,
    const float* __restrict__ wt1, const float* __restrict__ bp1,
    const float* __restrict__ wt2, const float* __restrict__ bp2,
    float* __restrict__ outF) {
#pragma clang fp contract(fast)
  __shared__ float XI[8][32][69];
  int blk = blockIdx.x;            // 2048 blocks: 128 per batch x 8 points
  int b = blk >> 7;
  int pb = (blk & 127) << 3;
  int t = threadIdx.x;

  for (int u = t; u < 8 * 32 * 67; u += 256) {
    int pt = u / (32 * 67);
    int r = u - pt * (32 * 67);
    int s = r / 67;
    int c = r - s * 67;
    int pp = pb + pt;
    int g = gidx[(size_t)((b << 10) + pp) * NSAMP + s];
    float val;
    if (c < 3)
      val = xyz[(size_t)(b * NPTS + g) * 3 + c] - nxyz[(size_t)((b << 10) + pp) * 3 + c];
    else
      val = featT[(size_t)(b * NPTS + g) * NCH + (c - 3)];
    XI[pt][s][c] = val;
  }
  __syncthreads();

  int lane = t & 63;
  int w = t >> 6;
  int lp = (w << 1) + (lane >> 5);  // local point 0..7 (own sample's point)
  int s = lane & 31;
  const float* xin = &XI[lp][s][0];

  f32x2 a[32], h[32];

  // ---- L0: 67 -> 64, acc in regs ----
  {
    const f32x2* bpv = (const f32x2*)bp0;
#pragma unroll
    for (int j = 0; j < 32; ++j) a[j] = bpv[j];
    for (int c = 0; c < 67; ++c) {
      float xv = xin[c];
      f32x2 xv2; xv2.x = xv; xv2.y = xv;
      const f32x2* wr = (const f32x2*)(wt0 + c * 64);
#pragma unroll
      for (int j = 0; j < 32; ++j) a[j] = a[j] + xv2 * wr[j];
    }
#pragma unroll
    for (int j = 0; j < 32; ++j) {
      h[j].x = fmaxf(a[j].x, 0.0f);
      h[j].y = fmaxf(a[j].y, 0.0f);
    }
  }

  // ---- L1: 64 -> 64, fully unrolled, register input ----
  {
    const f32x2* bpv = (const f32x2*)bp1;
#pragma unroll
    for (int j = 0; j < 32; ++j) a[j] = bpv[j];
#pragma unroll
    for (int c2 = 0; c2 < 32; ++c2) {
      f32x2 hv = h[c2];
      f32x2 x0; x0.x = hv.x; x0.y = hv.x;
      f32x2 x1; x1.x = hv.y; x1.y = hv.y;
      const f32x2* w0r = (const f32x2*)(wt1 + (2 * c2) * 64);
      const f32x2* w1r = (const f32x2*)(wt1 + (2 * c2 + 1) * 64);
#pragma unroll
      for (int j = 0; j < 32; ++j) a[j] = a[j] + x0 * w0r[j];
#pragma unroll
      for (int j = 0; j < 32; ++j) a[j] = a[j] + x1 * w1r[j];
    }
#pragma unroll
    for (int j = 0; j < 32; ++j) {
      h[j].x = fmaxf(a[j].x, 0.0f);
      h[j].y = fmaxf(a[j].y, 0.0f);
    }
  }

  // ---- L2: 64 -> 128 in two 64-channel halves; ReLU; DPP maxpool; store ----
  float* orow = outF + (size_t)((b << 10) + pb + lp) * 128;
#pragma unroll
  for (int half = 0; half < 2; ++half) {
    const f32x2* bpv = (const f32x2*)(bp2 + half * 64);
#pragma unroll
    for (int j = 0; j < 32; ++j) a[j] = bpv[j];
#pragma unroll
    for (int c2 = 0; c2 < 32; ++c2) {
      f32x2 hv = h[c2];
      f32x2 x0; x0.x = hv.x; x0.y = hv.x;
      f32x2 x1; x1.x = hv.y; x1.y = hv.y;
      const f32x2* w0r = (const f32x2*)(wt2 + (2 * c2) * 128 + half * 64);
      const f32x2* w1r = (const f32x2*)(wt2 + (2 * c2 + 1) * 128 + half * 64);
#pragma unroll
      for (int j = 0; j < 32; ++j) a[j] = a[j] + x0 * w0r[j];
#pragma unroll
      for (int j = 0; j < 32; ++j) a[j] = a[j] + x1 * w1r[j];
    }
#pragma unroll
    for (int j = 0; j < 32; ++j) {
      a[j].x = dppmax32(fmaxf(a[j].x, 0.0f));
      a[j].y = dppmax32(fmaxf(a[j].y, 0.0f));
    }
    if ((lane & 31) == 16) {  // lanes 16 / 48 hold their point's pooled half
      f32x2* od = (f32x2*)(orow + half * 64);
#pragma unroll
      for (int j = 0; j < 32; ++j) od[j] = a[j];
    }
  }
}

// ---------------------------------------------------------------------------
extern "C" void kernel_launch(void* const* d_in, const int* in_sizes, int n_in,
                              void* d_out, int out_size, void* d_ws, size_t ws_size,
                              hipStream_t stream) {
  if (n_in < 20 || ws_size < WS_NEED) return;
  const float* xyz = (const float*)d_in[0];
  const float* feat = (const float*)d_in[1];
  const float* W0 = (const float*)d_in[2];
  const float* b0 = (const float*)d_in[3];
  const float* g0 = (const float*)d_in[4];
  const float* be0 = (const float*)d_in[5];
  const float* m0 = (const float*)d_in[6];
  const float* v0 = (const float*)d_in[7];
  const float* W1 = (const float*)d_in[8];
  const float* b1 = (const float*)d_in[9];
  const float* g1 = (const float*)d_in[10];
  const float* be1 = (const float*)d_in[11];
  const float* m1 = (const float*)d_in[12];
  const float* v1 = (const float*)d_in[13];
  const float* W2 = (const float*)d_in[14];
  const float* b2 = (const float*)d_in[15];
  const float* g2 = (const float*)d_in[16];
  const float* be2 = (const float*)d_in[17];
  const float* m2 = (const float*)d_in[18];
  const float* v2 = (const float*)d_in[19];

  char* ws = (char*)d_ws;
  float* featT = (float*)(ws + OFF_FEATT);
  float* nxyz = (float*)(ws + OFF_NEWXYZ);
  int* gidx = (int*)(ws + OFF_GIDX);
  float* wt0 = (float*)(ws + OFF_WT0);
  float* bp0 = (float*)(ws + OFF_BP0);
  float* wt1 = (float*)(ws + OFF_WT1);
  float* bp1 = (float*)(ws + OFF_BP1);
  float* wt2 = (float*)(ws + OFF_WT2);
  float* bp2 = (float*)(ws + OFF_BP2);

  float* out_xyz = (float*)d_out;                         // [16,1024,3]
  float* out_feat = (float*)d_out + NBATCH * NPOINT * 3;  // [16,1024,128]

  hipLaunchKernelGGL(prep_kernel, dim3(1), dim3(256), 0, stream,
                     W0, b0, g0, be0, m0, v0, W1, b1, g1, be1, m1, v1,
                     W2, b2, g2, be2, m2, v2, wt0, bp0, wt1, bp1, wt2, bp2);
  hipLaunchKernelGGL(transpose_kernel, dim3(NPTS / 32, NCH / 32, NBATCH), dim3(32, 8), 0, stream,
                     feat, featT);
  hipLaunchKernelGGL(fps_kernel, dim3(NBATCH), dim3(256), 0, stream, xyz, nxyz, out_xyz);
  hipLaunchKernelGGL(topk_kernel, dim3(NBATCH * NPOINT / 4), dim3(256), 0, stream,
                     xyz, nxyz, gidx);
  hipLaunchKernelGGL(mlp_kernel, dim3(NBATCH * NPOINT / 8), dim3(256), 0, stream,
                     xyz, featT, nxyz, gidx, wt0, bp0, wt1, bp1, wt2, bp2, out_feat);
}

// Round 12
// 1245.825 us; speedup vs baseline: 1.4294x; 1.4294x over previous
//
#include <hip/hip_runtime.h>
#include <stdint.h>

#pragma clang fp contract(off)

typedef unsigned long long u64;
typedef float __attribute__((ext_vector_type(2))) f32x2;

#define NBATCH 16
#define NPTS   4096
#define NCH    64
#define NPOINT 1024
#define NSAMP  32

// ---- workspace byte offsets ----
#define OFF_FEATT   0u          // 16*4096*64*4 = 16777216
#define OFF_NEWXYZ  16777216u   // 16*1024*3*4 = 196608
#define OFF_GIDX    16973824u   // 16*1024*32*4 = 2097152
#define OFF_WT0     19070976u   // 67*64*4 = 17152
#define OFF_BP0     19088128u   // 64*4 (pad 256)
#define OFF_WT1     19088384u   // 64*64*4 = 16384
#define OFF_BP1     19104768u   // pad 256
#define OFF_WT2     19105024u   // 64*128*4 = 32768
#define OFF_BP2     19137792u   // pad 512
#define WS_NEED     19138304u

// Monotone map: float bits -> unsigned preserving total order (neg < pos).
__device__ __forceinline__ unsigned fkey(float f) {
  unsigned b = __float_as_uint(f);
  unsigned mask = ((unsigned)((int)b >> 31)) | 0x80000000u;
  return b ^ mask;
}

__device__ __forceinline__ double mkkey(float v, unsigned lo) {
  // key = (bits(v) << 32) | lo, viewed as double. v in [0, 1e10] -> positive
  // double, never NaN/Inf -> u64 order == f64 order -> fmax == u64 max.
  return __longlong_as_double((long long)(((u64)__float_as_uint(v) << 32) | lo));
}

__device__ __forceinline__ int mbcnt64(u64 m) {
  int c = __builtin_amdgcn_mbcnt_lo((unsigned)m, 0);
  return __builtin_amdgcn_mbcnt_hi((unsigned)(m >> 32), c);
}

// max over the 32-lane half this lane sits in; valid in lanes 16-31 / 48-63.
// Inputs are post-ReLU (>=0, no NaN) so fmaxf order-exact.
__device__ __forceinline__ float dppmax32(float v) {
  int x = __float_as_int(v);
#define DSTEP(CTRL)                                                        \
  {                                                                        \
    int y = __builtin_amdgcn_update_dpp(x, x, CTRL, 0xF, 0xF, false);      \
    v = fmaxf(v, __int_as_float(y));                                       \
    x = __float_as_int(v);                                                 \
  }
  DSTEP(0xB1)   // quad_perm xor1
  DSTEP(0x4E)   // quad_perm xor2
  DSTEP(0x124)  // row_ror:4
  DSTEP(0x128)  // row_ror:8   -> 16-rows uniform
  DSTEP(0x142)  // row_bcast15 -> lanes 16-31 / 48-63 hold the 32-half max
#undef DSTEP
  return v;
}

// ---------------------------------------------------------------------------
// Fold BN (eval) into conv weights/bias; transpose W to [c][o].
// ---------------------------------------------------------------------------
__global__ __launch_bounds__(256) void prep_kernel(
    const float* __restrict__ W0, const float* __restrict__ b0, const float* __restrict__ g0,
    const float* __restrict__ be0, const float* __restrict__ m0, const float* __restrict__ v0,
    const float* __restrict__ W1, const float* __restrict__ b1, const float* __restrict__ g1,
    const float* __restrict__ be1, const float* __restrict__ m1, const float* __restrict__ v1,
    const float* __restrict__ W2, const float* __restrict__ b2, const float* __restrict__ g2,
    const float* __restrict__ be2, const float* __restrict__ m2, const float* __restrict__ v2,
    float* __restrict__ wt0, float* __restrict__ bp0,
    float* __restrict__ wt1, float* __restrict__ bp1,
    float* __restrict__ wt2, float* __restrict__ bp2) {
  int t = threadIdx.x;
  for (int i = t; i < 64 * 67; i += 256) {
    int o = i / 67, c = i % 67;
    float s = g0[o] / sqrtf(v0[o] + 1e-5f);
    wt0[c * 64 + o] = W0[o * 67 + c] * s;
  }
  for (int o = t; o < 64; o += 256) {
    float s = g0[o] / sqrtf(v0[o] + 1e-5f);
    bp0[o] = (b0[o] - m0[o]) * s + be0[o];
  }
  for (int i = t; i < 64 * 64; i += 256) {
    int o = i / 64, c = i % 64;
    float s = g1[o] / sqrtf(v1[o] + 1e-5f);
    wt1[c * 64 + o] = W1[o * 64 + c] * s;
  }
  for (int o = t; o < 64; o += 256) {
    float s = g1[o] / sqrtf(v1[o] + 1e-5f);
    bp1[o] = (b1[o] - m1[o]) * s + be1[o];
  }
  for (int i = t; i < 128 * 64; i += 256) {
    int o = i / 64, c = i % 64;
    float s = g2[o] / sqrtf(v2[o] + 1e-5f);
    wt2[c * 128 + o] = W2[o * 64 + c] * s;
  }
  for (int o = t; o < 128; o += 256) {
    float s = g2[o] / sqrtf(v2[o] + 1e-5f);
    bp2[o] = (b2[o] - m2[o]) * s + be2[o];
  }
}

// ---------------------------------------------------------------------------
// features [B,C,N] -> featT [B,N,C]  (tiled 32x32 transpose)
// ---------------------------------------------------------------------------
__global__ __launch_bounds__(256) void transpose_kernel(const float* __restrict__ feat,
                                                        float* __restrict__ featT) {
  __shared__ float tile[32][33];
  int b = blockIdx.z;
  int n0 = blockIdx.x * 32;
  int c0 = blockIdx.y * 32;
  int tx = threadIdx.x, ty = threadIdx.y;  // 32 x 8
#pragma unroll
  for (int j = 0; j < 4; ++j)
    tile[ty + 8 * j][tx] = feat[b * (NCH * NPTS) + (c0 + ty + 8 * j) * NPTS + n0 + tx];
  __syncthreads();
#pragma unroll
  for (int j = 0; j < 4; ++j)
    featT[b * (NPTS * NCH) + (size_t)(n0 + ty + 8 * j) * NCH + c0 + tx] = tile[tx][ty + 8 * j];
}

// ---------------------------------------------------------------------------
// Exact farthest-point sampling. One block per batch, 256 threads x 16 pts
// (8x f32x2 packed). f64-key argmax (R4/R6 scheme). Measured 507 us (R9).
// ---------------------------------------------------------------------------
#define DPP_MAXSTEP(CTRL)                                                                          \
  do {                                                                                             \
    u64 kb_ = (u64)__double_as_longlong(key);                                                      \
    unsigned lo_ = (unsigned)kb_, hi_ = (unsigned)(kb_ >> 32);                                     \
    unsigned slo = (unsigned)__builtin_amdgcn_update_dpp((int)lo_, (int)lo_, CTRL, 0xF, 0xF, false); \
    unsigned shi = (unsigned)__builtin_amdgcn_update_dpp((int)hi_, (int)hi_, CTRL, 0xF, 0xF, false); \
    key = fmax(key, __longlong_as_double((long long)(((u64)shi << 32) | slo)));                    \
  } while (0)

__global__ __launch_bounds__(256) void fps_kernel(const float* __restrict__ xyz,
                                                  float* __restrict__ nxyz,
                                                  float* __restrict__ out_xyz) {
  __shared__ float sx[NPTS], sy[NPTS], sz[NPTS];
  __shared__ float outc[NPOINT][3];
  __shared__ double wkd[2][4];
  int b = blockIdx.x;
  int t = threadIdx.x;
  const float* X = xyz + (size_t)b * NPTS * 3;

  f32x2 qx[8], qy[8], qz[8], d2[8];
  unsigned nio[16];  // ~global_idx, loop-invariant key low words
#pragma unroll
  for (int i = 0; i < 8; ++i) {
    int p0 = t + 256 * (2 * i);
    int p1 = t + 256 * (2 * i + 1);
    float x0 = X[p0 * 3 + 0], y0 = X[p0 * 3 + 1], z0 = X[p0 * 3 + 2];
    float x1 = X[p1 * 3 + 0], y1 = X[p1 * 3 + 1], z1 = X[p1 * 3 + 2];
    qx[i].x = x0; qx[i].y = x1;
    qy[i].x = y0; qy[i].y = y1;
    qz[i].x = z0; qz[i].y = z1;
    sx[p0] = x0; sy[p0] = y0; sz[p0] = z0;
    sx[p1] = x1; sy[p1] = y1; sz[p1] = z1;
    d2[i].x = 1e10f; d2[i].y = 1e10f;
    nio[2 * i] = ~(unsigned)p0;
    nio[2 * i + 1] = ~(unsigned)p1;
  }
  __syncthreads();

  float lx = sx[0], ly = sy[0], lz = sz[0];
  if (t == 0) { outc[0][0] = lx; outc[0][1] = ly; outc[0][2] = lz; }

  for (int k = 1; k < NPOINT; ++k) {
    f32x2 vlx; vlx.x = lx; vlx.y = lx;
    f32x2 vly; vly.x = ly; vly.y = ly;
    f32x2 vlz; vlz.x = lz; vlz.y = lz;
    // distance update: contract(off), exact per-component order (dx^2+dy^2)+dz^2
#pragma unroll
    for (int i = 0; i < 8; ++i) {
      f32x2 dx = qx[i] - vlx, dy = qy[i] - vly, dz = qz[i] - vlz;
      f32x2 dist = (dx * dx + dy * dy) + dz * dz;
      d2[i] = __builtin_elementwise_min(d2[i], dist);
    }
    // 16 keys -> 15 v_max_f64 tree
    double k0 = fmax(mkkey(d2[0].x, nio[0]), mkkey(d2[0].y, nio[1]));
    double k1 = fmax(mkkey(d2[1].x, nio[2]), mkkey(d2[1].y, nio[3]));
    double k2 = fmax(mkkey(d2[2].x, nio[4]), mkkey(d2[2].y, nio[5]));
    double k3 = fmax(mkkey(d2[3].x, nio[6]), mkkey(d2[3].y, nio[7]));
    double k4 = fmax(mkkey(d2[4].x, nio[8]), mkkey(d2[4].y, nio[9]));
    double k5 = fmax(mkkey(d2[5].x, nio[10]), mkkey(d2[5].y, nio[11]));
    double k6 = fmax(mkkey(d2[6].x, nio[12]), mkkey(d2[6].y, nio[13]));
    double k7 = fmax(mkkey(d2[7].x, nio[14]), mkkey(d2[7].y, nio[15]));
    k0 = fmax(k0, k1); k2 = fmax(k2, k3); k4 = fmax(k4, k5); k6 = fmax(k6, k7);
    k0 = fmax(k0, k2); k4 = fmax(k4, k6);
    double key = fmax(k0, k4);

    // wave64 max-reduce; lane 63 ends with the wave max
    DPP_MAXSTEP(0xB1);   // quad_perm xor1
    DPP_MAXSTEP(0x4E);   // quad_perm xor2
    DPP_MAXSTEP(0x124);  // row_ror:4
    DPP_MAXSTEP(0x128);  // row_ror:8
    DPP_MAXSTEP(0x142);  // row_bcast15
    DPP_MAXSTEP(0x143);  // row_bcast31

    int kb = k & 1;
    if ((t & 63) == 63) wkd[kb][t >> 6] = key;
    __syncthreads();
    double w0 = wkd[kb][0], w1 = wkd[kb][1], w2 = wkd[kb][2], w3 = wkd[kb][3];
    w0 = fmax(w0, w1); w2 = fmax(w2, w3);
    w0 = fmax(w0, w2);
    int last = (int)(~(unsigned)(u64)__double_as_longlong(w0));
    lx = sx[last]; ly = sy[last]; lz = sz[last];  // broadcast LDS reads
    if (t == 0) { outc[k][0] = lx; outc[k][1] = ly; outc[k][2] = lz; }
    // no second barrier: wkd double-buffered on k&1
  }
  __syncthreads();
  for (int p = t; p < NPOINT; p += 256) {
    float x = outc[p][0], y = outc[p][1], z = outc[p][2];
    int o = (b * NPOINT + p) * 3;
    nxyz[o] = x; nxyz[o + 1] = y; nxyz[o + 2] = z;
    out_xyz[o] = x; out_xyz[o + 1] = y; out_xyz[o + 2] = z;
  }
}

// ---------------------------------------------------------------------------
// 32 nearest neighbors per sampled point — wave-per-query radix-rank select.
// Registers-only, no LDS, no barriers (R8: part of the -210us gain).
// ---------------------------------------------------------------------------
__global__ __launch_bounds__(256) void topk_kernel(const float* __restrict__ xyz,
                                                   const float* __restrict__ nxyz,
                                                   int* __restrict__ gidx) {
  int wq = (blockIdx.x << 2) + (threadIdx.x >> 6);  // query id: b*1024 + p
  int lane = threadIdx.x & 63;
  int b = wq >> 10;
  const float* X = xyz + (size_t)b * NPTS * 3;
  float px = nxyz[wq * 3 + 0], py = nxyz[wq * 3 + 1], pz = nxyz[wq * 3 + 2];
  float n2p = (px * px + py * py) + pz * pz;

  unsigned ukey[64];
#pragma unroll
  for (int i = 0; i < 64; ++i) {
    int n = i * 64 + lane;
    float x = X[n * 3 + 0], y = X[n * 3 + 1], z = X[n * 3 + 2];
    float n2x = (x * x + y * y) + z * z;
    float dot = fmaf(pz, z, fmaf(py, y, px * x));
    float sq = (n2p + n2x) - 2.0f * dot;
    ukey[i] = fkey(sq);
  }

  // V* = max V with count(ukey < V) <= 31  == 32nd-smallest ukey value
  unsigned V = 0u;
  for (int bit = 31; bit >= 0; --bit) {
    unsigned cand = V | (1u << bit);
    int cnt = 0;
#pragma unroll
    for (int i = 0; i < 64; ++i)
      cnt += __popcll(__ballot(ukey[i] < cand));
    if (cnt <= 31) V = cand;
  }

  int* go = gidx + (size_t)wq * NSAMP;
  int base = 0;
#pragma unroll
  for (int i = 0; i < 64; ++i) {  // all strictly-below-threshold keys
    bool lt = ukey[i] < V;
    u64 m = __ballot(lt);
    if (lt) go[base + mbcnt64(m)] = i * 64 + lane;
    base += __popcll(m);
  }
#pragma unroll
  for (int i = 0; i < 64; ++i) {  // fill from ==V* by ascending idx
    bool eq = (ukey[i] == V);
    u64 m = __ballot(eq);
    if (eq) {
      int pos = base + mbcnt64(m);
      if (pos < NSAMP) go[pos] = i * 64 + lane;
    }
    base += __popcll(m);
  }
}

// ---------------------------------------------------------------------------
// Gather + 3-layer pointwise MLP (BN folded) + max over 32 samples.
// R12: back to the loop-based 2-point block (small code — R11 lesson: full
// unroll = 66 KB body blew the 32 KB L1I, 990us). NEW: active layer weights
// staged in LDS WB (<=17 KB, coalesced once per block); inner loops read
// weight rows via BROADCAST ds_read (same addr all lanes -> conflict-free,
// never misses) instead of s_load streams missing the 16 KB scalar L1.
// #pragma unroll 2 caps code size. wt2 staged as two 16 KB output-halves.
// LDS 35+17 KB -> 3 blocks/CU (12 waves). DPP maxpool (VALU, no shuffles).
// ---------------------------------------------------------------------------
__global__ __launch_bounds__(256) void mlp_kernel(
    const float* __restrict__ xyz, const float* __restrict__ featT,
    const float* __restrict__ nxyz, const int* __restrict__ gidx,
    const float* __restrict__ wt0, const float* __restrict__ bp0,
    const float* __restrict__ wt1, const float* __restrict__ bp1,
    const float* __restrict__ wt2, const float* __restrict__ bp2,
    float* __restrict__ outF) {
#pragma clang fp contract(fast)
  __shared__ float XA[2][32][69];
  __shared__ float XB[2][32][69];
  __shared__ float WB[4288];
  int blk = blockIdx.x;
  int b = blk >> 9;
  int pb = (blk & 511) << 1;
  int t = threadIdx.x;

  // stage L0 weights + gather input
  for (int i = t; i < 4288; i += 256) WB[i] = wt0[i];
  for (int u = t; u < 2 * 32 * 67; u += 256) {
    int pt = u / (32 * 67);
    int r = u - pt * (32 * 67);
    int s = r / 67;
    int c = r - s * 67;
    int pp = pb + pt;
    int g = gidx[(size_t)((b << 10) + pp) * NSAMP + s];
    float val;
    if (c < 3)
      val = xyz[(size_t)(b * NPTS + g) * 3 + c] - nxyz[(size_t)((b << 10) + pp) * 3 + c];
    else
      val = featT[(size_t)(b * NPTS + g) * NCH + (c - 3)];
    XA[pt][s][c] = val;
  }
  __syncthreads();

  int w = t >> 6;
  int l = t & 63;
  int s = l & 31;
  int pt = l >> 5;
  int ob = w * 16;

  {  // L0: XA[*,*,0:67] -> XB[*,*,0:64], weights from WB
    f32x2 acc[8];
    const f32x2* bpv = (const f32x2*)(bp0 + ob);
#pragma unroll
    for (int j = 0; j < 8; ++j) acc[j] = bpv[j];
#pragma unroll 2
    for (int c = 0; c < 67; ++c) {
      float xv = XA[pt][s][c];
      f32x2 xv2; xv2.x = xv; xv2.y = xv;
      const f32x2* wr = (const f32x2*)(WB + c * 64 + ob);
#pragma unroll
      for (int j = 0; j < 8; ++j) acc[j] = acc[j] + xv2 * wr[j];
    }
#pragma unroll
    for (int j = 0; j < 8; ++j) {
      XB[pt][s][ob + 2 * j] = fmaxf(acc[j].x, 0.0f);
      XB[pt][s][ob + 2 * j + 1] = fmaxf(acc[j].y, 0.0f);
    }
  }
  __syncthreads();  // L0 done: WB(wt0) reads + XB writes complete

  for (int i = t; i < 4096; i += 256) WB[i] = wt1[i];
  __syncthreads();

  {  // L1: XB -> XA
    f32x2 acc[8];
    const f32x2* bpv = (const f32x2*)(bp1 + ob);
#pragma unroll
    for (int j = 0; j < 8; ++j) acc[j] = bpv[j];
#pragma unroll 2
    for (int c = 0; c < 64; ++c) {
      float xv = XB[pt][s][c];
      f32x2 xv2; xv2.x = xv; xv2.y = xv;
      const f32x2* wr = (const f32x2*)(WB + c * 64 + ob);
#pragma unroll
      for (int j = 0; j < 8; ++j) acc[j] = acc[j] + xv2 * wr[j];
    }
#pragma unroll
    for (int j = 0; j < 8; ++j) {
      XA[pt][s][ob + 2 * j] = fmaxf(acc[j].x, 0.0f);
      XA[pt][s][ob + 2 * j + 1] = fmaxf(acc[j].y, 0.0f);
    }
  }
  __syncthreads();  // L1 done

  // L2 in two 64-output halves; wave w owns [half*64 + ob, +16)
  float* orow = outF + (size_t)((b << 10) + pb + pt) * 128;
#pragma unroll 1
  for (int half = 0; half < 2; ++half) {
    for (int i = t; i < 4096; i += 256) {
      int c = i >> 6, o = i & 63;
      WB[i] = wt2[c * 128 + half * 64 + o];
    }
    __syncthreads();
    f32x2 acc[8];
    const f32x2* bpv = (const f32x2*)(bp2 + half * 64 + ob);
#pragma unroll
    for (int j = 0; j < 8; ++j) acc[j] = bpv[j];
#pragma unroll 2
    for (int c = 0; c < 64; ++c) {
      float xv = XA[pt][s][c];
      f32x2 xv2; xv2.x = xv; xv2.y = xv;
      const f32x2* wr = (const f32x2*)(WB + c * 64 + ob);
#pragma unroll
      for (int j = 0; j < 8; ++j) acc[j] = acc[j] + xv2 * wr[j];
    }
#pragma unroll
    for (int j = 0; j < 8; ++j) {
      acc[j].x = dppmax32(fmaxf(acc[j].x, 0.0f));
      acc[j].y = dppmax32(fmaxf(acc[j].y, 0.0f));
    }
    if ((l & 31) == 16) {  // lanes 16 / 48 hold their point's pooled values
      f32x2* od = (f32x2*)(orow + half * 64 + ob);
#pragma unroll
      for (int j = 0; j < 8; ++j) od[j] = acc[j];
    }
    __syncthreads();  // WB reads done before next half's staging
  }
}

// ---------------------------------------------------------------------------
extern "C" void kernel_launch(void* const* d_in, const int* in_sizes, int n_in,
                              void* d_out, int out_size, void* d_ws, size_t ws_size,
                              hipStream_t stream) {
  if (n_in < 20 || ws_size < WS_NEED) return;
  const float* xyz = (const float*)d_in[0];
  const float* feat = (const float*)d_in[1];
  const float* W0 = (const float*)d_in[2];
  const float* b0 = (const float*)d_in[3];
  const float* g0 = (const float*)d_in[4];
  const float* be0 = (const float*)d_in[5];
  const float* m0 = (const float*)d_in[6];
  const float* v0 = (const float*)d_in[7];
  const float* W1 = (const float*)d_in[8];
  const float* b1 = (const float*)d_in[9];
  const float* g1 = (const float*)d_in[10];
  const float* be1 = (const float*)d_in[11];
  const float* m1 = (const float*)d_in[12];
  const float* v1 = (const float*)d_in[13];
  const float* W2 = (const float*)d_in[14];
  const float* b2 = (const float*)d_in[15];
  const float* g2 = (const float*)d_in[16];
  const float* be2 = (const float*)d_in[17];
  const float* m2 = (const float*)d_in[18];
  const float* v2 = (const float*)d_in[19];

  char* ws = (char*)d_ws;
  float* featT = (float*)(ws + OFF_FEATT);
  float* nxyz = (float*)(ws + OFF_NEWXYZ);
  int* gidx = (int*)(ws + OFF_GIDX);
  float* wt0 = (float*)(ws + OFF_WT0);
  float* bp0 = (float*)(ws + OFF_BP0);
  float* wt1 = (float*)(ws + OFF_WT1);
  float* bp1 = (float*)(ws + OFF_BP1);
  float* wt2 = (float*)(ws + OFF_WT2);
  float* bp2 = (float*)(ws + OFF_BP2);

  float* out_xyz = (float*)d_out;                         // [16,1024,3]
  float* out_feat = (float*)d_out + NBATCH * NPOINT * 3;  // [16,1024,128]

  hipLaunchKernelGGL(prep_kernel, dim3(1), dim3(256), 0, stream,
                     W0, b0, g0, be0, m0, v0, W1, b1, g1, be1, m1, v1,
                     W2, b2, g2, be2, m2, v2, wt0, bp0, wt1, bp1, wt2, bp2);
  hipLaunchKernelGGL(transpose_kernel, dim3(NPTS / 32, NCH / 32, NBATCH), dim3(32, 8), 0, stream,
                     feat, featT);
  hipLaunchKernelGGL(fps_kernel, dim3(NBATCH), dim3(256), 0, stream, xyz, nxyz, out_xyz);
  hipLaunchKernelGGL(topk_kernel, dim3(NBATCH * NPOINT / 4), dim3(256), 0, stream,
                     xyz, nxyz, gidx);
  hipLaunchKernelGGL(mlp_kernel, dim3(NBATCH * NPOINT / 2), dim3(256), 0, stream,
                     xyz, featT, nxyz, gidx, wt0, bp0, wt1, bp1, wt2, bp2, out_feat);
}